// Round 3
// baseline (302.374 us; speedup 1.0000x reference)
//
#include <hip/hip_runtime.h>
#include <math.h>

#define NUM_KV_HEADS 8
#define HEAD_DIM 128
#define HD (NUM_KV_HEADS * HEAD_DIM)
#define BLOCK_SZ 16
#define MODEL_CTX 4096
#define CHUNK 128            // tokens per split-K chunk
#define BLKS_PER_CHUNK (CHUNK / BLOCK_SZ)   // 8

// Kernel 0: rope cos/sin table. float4 at (t*128 + 4*f2) = {cos(f0),sin(f0),cos(f1),sin(f1)}
// for f0=2*f2, f1=2*f2+1 (f2 = sub-lane 0..31).
__global__ void rope_table(float* __restrict__ tab, int ntab) {
    const int idx = blockIdx.x * 256 + threadIdx.x;   // t*64 + f
    if (idx >= ntab * 64) return;
    const int t = idx >> 6;
    const int f = idx & 63;
    const float inv = expf(-9.210340371976184f * (float)f * (1.0f / 64.0f));
    float s, c;
    sincosf((float)t * inv, &s, &c);
    tab[2 * idx]     = c;
    tab[2 * idx + 1] = s;
}

struct Batch {
    float2 ka[4], kb[4], va[4], vb[4];
    float4 cs[4];
};

// Kernel 1: per-(chunk, b*h) partial attention. Each half-wave (32 lanes) owns
// 16 consecutive tokens, streamed with online softmax: K+V+cos/sin for 4 tokens
// loaded together, two batches in flight, NO block-wide barrier until the final
// 8-half-wave combine. Lane sl holds dims {2sl,2sl+1,64+2sl,65+2sl}.
__global__ __launch_bounds__(256, 4)
void attn_partial(const float* __restrict__ q,
                  const float* __restrict__ knew,
                  const float* __restrict__ vnew,
                  const float* __restrict__ kcache,
                  const float* __restrict__ vcache,
                  const int* __restrict__ btab,
                  const int* __restrict__ seqlen_p,
                  const float* __restrict__ tab,
                  int nbps,
                  float* __restrict__ o_part,    // [B*H][n_chunks][128]
                  float* __restrict__ m_part,    // [B*H][n_chunks]
                  float* __restrict__ l_part,    // [B*H][n_chunks]
                  int n_chunks)
{
    const int chunk = blockIdx.x;
    const int bh    = blockIdx.y;
    const int b     = bh / NUM_KV_HEADS;
    const int h     = bh % NUM_KV_HEADS;
    const int tid   = threadIdx.x;
    const int lane  = tid & 63;
    const int wave  = tid >> 6;
    const int sl    = lane & 31;
    const int half  = lane >> 5;
    const int hw    = wave * 2 + half;    // half-wave 0..7

    const int seq_len = *seqlen_p;
    const int rem = (seq_len - 1) & (BLOCK_SZ - 1);
    const int T   = (nbps - 1) * BLOCK_SZ + rem + 1;

    // this half-wave's cache block (32-lane broadcast load of one dword)
    const int blk = btab[b * nbps + chunk * BLKS_PER_CHUNK + hw];
    const size_t head_off = (size_t)h * HEAD_DIM;
    const float* kbase = kcache + (size_t)blk * BLOCK_SZ * HD + head_off;
    const float* vbase = vcache + (size_t)blk * BLOCK_SZ * HD + head_off;
    const float* knb = knew + (size_t)b * HD + head_off;
    const float* vnb = vnew + (size_t)b * HD + head_off;
    const int tbase = chunk * CHUNK + hw * BLOCK_SZ;

    // rope q at pos MODEL_CTX-1 via table
    const float* qb = q + (size_t)b * HD + head_off;
    const float2 qa  = *(const float2*)(qb + 2 * sl);
    const float2 qb2 = *(const float2*)(qb + 64 + 2 * sl);
    const float4 qcs = *(const float4*)(tab + (size_t)(MODEL_CTX - 1) * 128 + 4 * sl);
    const float qr1a = qa.x * qcs.x - qb2.x * qcs.y;
    const float qr1b = qa.y * qcs.z - qb2.y * qcs.w;
    const float qr2a = qb2.x * qcs.x + qa.x * qcs.y;
    const float qr2b = qb2.y * qcs.z + qa.y * qcs.w;

    const float scale = 0.08838834764831845f;   // 1/sqrt(128)

    // online-softmax state
    float m = -INFINITY, l = 0.f;
    float a1a = 0.f, a1b = 0.f, a2a = 0.f, a2b = 0.f;

    auto load_batch = [&](Batch& B, int j4) {
        #pragma unroll
        for (int u = 0; u < 4; u++) {
            const int j = j4 + u;
            const int t = tbase + j;
            const bool nl = (t >= T - 1);          // new-token (or OOB; masked later)
            const float* kp = nl ? knb : (kbase + (size_t)j * HD);
            const float* vp = nl ? vnb : (vbase + (size_t)j * HD);
            const int tt    = nl ? (MODEL_CTX - 1) : t;
            B.ka[u] = *(const float2*)(kp + 2 * sl);
            B.kb[u] = *(const float2*)(kp + 64 + 2 * sl);
            B.va[u] = *(const float2*)(vp + 2 * sl);
            B.vb[u] = *(const float2*)(vp + 64 + 2 * sl);
            B.cs[u] = *(const float4*)(tab + (size_t)tt * 128 + 4 * sl);
        }
    };

    auto compute_batch = [&](const Batch& B, int j4) {
        if (tbase + j4 >= T) return;               // whole batch OOB
        float s[4];
        #pragma unroll
        for (int u = 0; u < 4; u++) {
            const float r1a = B.ka[u].x * B.cs[u].x - B.kb[u].x * B.cs[u].y;
            const float r1b = B.ka[u].y * B.cs[u].z - B.kb[u].y * B.cs[u].w;
            const float r2a = B.kb[u].x * B.cs[u].x + B.ka[u].x * B.cs[u].y;
            const float r2b = B.kb[u].y * B.cs[u].z + B.ka[u].y * B.cs[u].w;
            float d = r1a * qr1a + r1b * qr1b + r2a * qr2a + r2b * qr2b;
            #pragma unroll
            for (int off = 1; off < 32; off <<= 1) d += __shfl_xor(d, off, 64);
            s[u] = (tbase + j4 + u < T) ? d * scale : -INFINITY;
        }
        const float mb = fmaxf(fmaxf(s[0], s[1]), fmaxf(s[2], s[3]));
        const float m_new = fmaxf(m, mb);          // finite: s[0] valid here
        const float alpha = __expf(m - m_new);     // first batch: exp(-inf)=0
        float p[4];
        #pragma unroll
        for (int u = 0; u < 4; u++) p[u] = __expf(s[u] - m_new);  // -inf -> 0
        l = l * alpha + (p[0] + p[1] + p[2] + p[3]);
        a1a = a1a * alpha + p[0]*B.va[0].x + p[1]*B.va[1].x + p[2]*B.va[2].x + p[3]*B.va[3].x;
        a1b = a1b * alpha + p[0]*B.va[0].y + p[1]*B.va[1].y + p[2]*B.va[2].y + p[3]*B.va[3].y;
        a2a = a2a * alpha + p[0]*B.vb[0].x + p[1]*B.vb[1].x + p[2]*B.vb[2].x + p[3]*B.vb[3].x;
        a2b = a2b * alpha + p[0]*B.vb[0].y + p[1]*B.vb[1].y + p[2]*B.vb[2].y + p[3]*B.vb[3].y;
        m = m_new;
    };

    // software pipeline: two 4-token batches in flight
    Batch b0, b1;
    load_batch(b0, 0);
    load_batch(b1, 4);
    compute_batch(b0, 0);
    load_batch(b0, 8);
    compute_batch(b1, 4);
    load_batch(b1, 12);
    compute_batch(b0, 8);
    compute_batch(b1, 12);

    // ---- combine 8 half-waves (single barrier) ----
    __shared__ float po[8][HEAD_DIM];
    __shared__ float sm[8];
    __shared__ float slw[8];
    po[hw][2 * sl]      = a1a;
    po[hw][2 * sl + 1]  = a1b;
    po[hw][64 + 2 * sl] = a2a;
    po[hw][65 + 2 * sl] = a2b;
    if (sl == 0) { sm[hw] = m; slw[hw] = l; }
    __syncthreads();

    if (tid < HEAD_DIM) {
        float M = sm[0];
        #pragma unroll
        for (int j = 1; j < 8; j++) M = fmaxf(M, sm[j]);
        float L = 0.f, num = 0.f;
        #pragma unroll
        for (int j = 0; j < 8; j++) {
            const float w = __expf(sm[j] - M);
            L   += w * slw[j];
            num += w * po[j][tid];
        }
        o_part[((size_t)bh * n_chunks + chunk) * HEAD_DIM + tid] = num;
        if (tid == 0) {
            m_part[bh * n_chunks + chunk] = M;
            l_part[bh * n_chunks + chunk] = L;
        }
    }
}

// Kernel 2: combine split-K partials.
__global__ void attn_combine(const float* __restrict__ o_part,
                             const float* __restrict__ m_part,
                             const float* __restrict__ l_part,
                             float* __restrict__ out,
                             int n_chunks)
{
    const int bh = blockIdx.x;
    const int d  = threadIdx.x;

    float M = -INFINITY;
    for (int c = 0; c < n_chunks; c++) M = fmaxf(M, m_part[bh * n_chunks + c]);
    float L = 0.f, num = 0.f;
    for (int c = 0; c < n_chunks; c++) {
        const float w = __expf(m_part[bh * n_chunks + c] - M);
        L   += l_part[bh * n_chunks + c] * w;
        num += w * o_part[((size_t)bh * n_chunks + c) * HEAD_DIM + d];
    }
    out[(size_t)bh * HEAD_DIM + d] = num / L;
}

extern "C" void kernel_launch(void* const* d_in, const int* in_sizes, int n_in,
                              void* d_out, int out_size, void* d_ws, size_t ws_size,
                              hipStream_t stream) {
    const float* q  = (const float*)d_in[0];
    const float* k  = (const float*)d_in[1];
    const float* v  = (const float*)d_in[2];
    const float* kc = (const float*)d_in[3];
    const float* vc = (const float*)d_in[4];
    const int* bt   = (const int*)d_in[5];
    const int* slp  = (const int*)d_in[7];

    const int B    = in_sizes[0] / HD;
    const int nbps = in_sizes[5] / B;                              // 256
    const int n_chunks = (nbps * BLOCK_SZ + CHUNK - 1) / CHUNK;    // 32
    const int BH = B * NUM_KV_HEADS;

    int ntab = nbps * BLOCK_SZ;
    if (ntab < MODEL_CTX) ntab = MODEL_CTX;

    float* tab    = (float*)d_ws;                                   // ntab*128 floats
    float* o_part = tab + (size_t)ntab * 128;
    float* m_part = o_part + (size_t)BH * n_chunks * HEAD_DIM;
    float* l_part = m_part + (size_t)BH * n_chunks;

    const int ttotal = ntab * 64;
    rope_table<<<(ttotal + 255) / 256, 256, 0, stream>>>(tab, ntab);

    dim3 g1(n_chunks, BH);
    attn_partial<<<g1, 256, 0, stream>>>(q, k, v, kc, vc, bt, slp, tab, nbps,
                                         o_part, m_part, l_part, n_chunks);
    attn_combine<<<dim3(BH), HEAD_DIM, 0, stream>>>(o_part, m_part, l_part,
                                                    (float*)d_out, n_chunks);
}